// Round 4
// baseline (300.449 us; speedup 1.0000x reference)
//
#include <hip/hip_runtime.h>
#include <stdint.h>

#define R 128
#define NB 64

// workspace float offsets
#define CAM0_OFF 0          // 64*128*784 = 6422528
#define CAM1_OFF 6422528    // 64*128*196 = 1605632
#define CAM2_OFF 8028160    // 64*128*49  = 401408
#define POOL0_OFF 8429568   // 1605632
#define POOL1_OFF 10035200  // 401408
#define WB_OFF    10436608  // 458752 bf16 = 229376 float slots
#define PART_OFF  10665984  // 2*16384*64 = 2097152  (layout [b][lk*16384+m*128+n])
#define NORM_OFF  12763136  // 2*8192 inv-norms (cam1 rows, cam2 rows)
// total 12779520 floats ~= 48.8 MiB

typedef __bf16 bf16;
typedef bf16 v2bf __attribute__((ext_vector_type(2)));
typedef bf16 v8bf __attribute__((ext_vector_type(8)));
typedef float f4v __attribute__((ext_vector_type(4)));

// lgkm-only barrier: keeps global loads in flight across the barrier
#define ASM_BARRIER() asm volatile("s_waitcnt lgkmcnt(0)\n\ts_barrier" ::: "memory")

// ---------------- prep: w fp32 -> bf16 (row-major, levels concatenated) -----
__global__ void prep_w(const float* __restrict__ w0, const float* __restrict__ w1,
                       const float* __restrict__ w2, bf16* __restrict__ wb) {
    int id = blockIdx.x * 256 + threadIdx.x;   // < 458752 exact
    float v;
    if (id < 65536)       v = w0[id];
    else if (id < 196608) v = w1[id - 65536];
    else                  v = w2[id - 196608];
    wb[id] = (bf16)v;
}

// ---------------- cam GEMM: cam[b,r,i] = sum_c w[r,c]*fmap[b,c,i] ----------
// 512 threads (8 waves of 32m x 32n), BM=128 BN=64 BK=128.
// BK=128: half the barriers/iters of BK=64; 32 MFMA per wave per iter so the
// per-iter fixed costs (lgkm drain, barrier, ds_read+A-frag latency) amortize.
// Double-buffered LDS + depth-2 register prefetch (same in-flight bytes as
// the old BK=64 depth-4), one lgkm-only barrier per K-iter.
__global__ __launch_bounds__(512) void cam_gemm(
    const float* __restrict__ f0, const float* __restrict__ f1,
    const float* __restrict__ f2, const bf16* __restrict__ wb,
    float* __restrict__ ws) {
    __shared__ bf16 ldsB[2][64 * 136];   // [buf][i(64)][k-chunks(16)+pad], 272 B row

    int bid = blockIdx.x, tid = threadIdx.x;
    int lvl, b, i0;
    if (bid < 64)       { lvl = 2; b = bid; i0 = 0; }              // heavy first
    else if (bid < 320) { int t = bid - 64; lvl = 1; b = t >> 2;
                          int ti = t & 3; i0 = ti < 3 ? ti * 64 : 132; }
    else                { int t = bid - 320; lvl = 0; b = t / 13;
                          int ti = t - b * 13; i0 = ti < 12 ? ti * 64 : 720; }
    const int C  = (lvl == 0) ? 512 : (lvl == 1) ? 1024 : 2048;
    const int HW = (lvl == 0) ? 784 : (lvl == 1) ? 196  : 49;
    const float* fmap = (lvl == 0) ? f0 : (lvl == 1) ? f1 : f2;
    const bf16*  wbl  = wb + ((lvl == 0) ? 0 : (lvl == 1) ? 65536 : 196608);
    float* cam = ws + ((lvl == 0) ? CAM0_OFF : (lvl == 1) ? CAM1_OFF : CAM2_OFF);

    // staging decode: 2 units/thread; unit = 2 k-rows x 4 i.
    // unit0: k-pairs d (k=2d,2d+1), unit1: k-pairs d+32 (chunk +8 -> +64 bf16)
    int d = tid >> 4;                 // k-pair id 0..31
    int ku2 = d * 2;
    int i4 = (tid & 15) * 4;
    int gbase = b * C * HW + ku2 * HW + i0 + i4;
    int ldsd[4];
    int i4c[4];
#pragma unroll
    for (int e = 0; e < 4; ++e) {
        int i = i4 + e;               // LDS row (n-local)
        int grp = (d >> 2) ^ ((i >> 3) & 7);     // chunk 0..7 ^ 3-bit row xor
        ldsd[e] = i * 136 + grp * 8 + (d & 3) * 2;   // bf16 units
        i4c[e] = min(i, 48);          // clamp for HW==49 path
    }
    const int lane = tid & 63, wave = tid >> 6;
    const int lm = lane & 15, q = lane >> 4;
    const int wm = (wave >> 1) * 32, wn = (wave & 1) * 32;
    int irow[2], ixor[2];
#pragma unroll
    for (int sn = 0; sn < 2; ++sn) {
        irow[sn] = wn + sn * 16 + lm;
        ixor[sn] = (irow[sn] >> 3) & 7;
    }
    const bf16* arow[2];
#pragma unroll
    for (int sm = 0; sm < 2; ++sm)
        arow[sm] = wbl + (wm + sm * 16 + lm) * C + q * 8;

    // r[0..1] = unit0 (k-rows ku2, ku2+1), r[2..3] = unit1 (k-rows ku2+64, +65)
    auto loadT = [&](int kc, float4 (&r)[4]) {
        if (HW != 49) {
            const float* p = fmap + gbase + kc * HW;
            r[0] = *(const float4*)p;
            r[1] = *(const float4*)(p + HW);
            r[2] = *(const float4*)(p + 64 * HW);
            r[3] = *(const float4*)(p + 65 * HW);
        } else {
            const float* p = fmap + b * C * 49 + (kc + ku2) * 49;
#pragma unroll
            for (int u = 0; u < 2; ++u) {
                const float* pu = p + u * 64 * 49;
                r[2 * u].x = pu[i4c[0]]; r[2 * u].y = pu[i4c[1]];
                r[2 * u].z = pu[i4c[2]]; r[2 * u].w = pu[i4c[3]];
                r[2 * u + 1].x = pu[49 + i4c[0]]; r[2 * u + 1].y = pu[49 + i4c[1]];
                r[2 * u + 1].z = pu[49 + i4c[2]]; r[2 * u + 1].w = pu[49 + i4c[3]];
            }
        }
    };
    auto stage = [&](float4 (&r)[4], bf16* buf) {
#pragma unroll
        for (int u = 0; u < 2; ++u) {
            v2bf t0 = { (bf16)r[2 * u].x, (bf16)r[2 * u + 1].x };
            v2bf t1 = { (bf16)r[2 * u].y, (bf16)r[2 * u + 1].y };
            v2bf t2 = { (bf16)r[2 * u].z, (bf16)r[2 * u + 1].z };
            v2bf t3 = { (bf16)r[2 * u].w, (bf16)r[2 * u + 1].w };
            int off = u * 64;          // unit1 chunks +8 -> +64 bf16 units
            *(v2bf*)&buf[ldsd[0] + off] = t0;
            *(v2bf*)&buf[ldsd[1] + off] = t1;
            *(v2bf*)&buf[ldsd[2] + off] = t2;
            *(v2bf*)&buf[ldsd[3] + off] = t3;
        }
    };

    f4v acc[2][2] = {};
    auto comp = [&](int kc, const bf16* buf) {
#pragma unroll
        for (int ksi = 0; ksi < 4; ++ksi) {
            v8bf af[2];
#pragma unroll
            for (int sm = 0; sm < 2; ++sm)
                af[sm] = *(const v8bf*)(arow[sm] + kc + ksi * 32);
            v8bf bfr[2];
#pragma unroll
            for (int sn = 0; sn < 2; ++sn) {
                int grp = (q + ksi * 4) ^ ixor[sn];
                bfr[sn] = *(const v8bf*)&buf[irow[sn] * 136 + grp * 8];
            }
#pragma unroll
            for (int sm = 0; sm < 2; ++sm)
#pragma unroll
                for (int sn = 0; sn < 2; ++sn)
                    acc[sm][sn] = __builtin_amdgcn_mfma_f32_16x16x32_bf16(
                        af[sm], bfr[sn], acc[sm][sn], 0, 0, 0);
        }
    };

    const int nIter = C >> 7;       // 4 / 8 / 16, always even
    float4 rA[4], rB[4];
    loadT(0, rA);
    loadT(128, rB);
    for (int t = 0; t < nIter; t += 2) {
        stage(rA, ldsB[0]);          // waits rA only (vmcnt keeps rB flying)
        ASM_BARRIER();
        if (t + 2 < nIter) loadT((t + 2) << 7, rA);
        comp(t << 7, ldsB[0]);
        stage(rB, ldsB[1]);
        ASM_BARRIER();
        if (t + 3 < nIter) loadT((t + 3) << 7, rB);
        comp((t + 1) << 7, ldsB[1]);
    }
    // epilogue: D row = q*4+reg, col = lm
#pragma unroll
    for (int sn = 0; sn < 2; ++sn) {
        int i_n = i0 + irow[sn];
        if (i_n < HW) {
            int base = (b * R) * HW + i_n;
#pragma unroll
            for (int sm = 0; sm < 2; ++sm) {
#pragma unroll
                for (int reg = 0; reg < 4; ++reg) {
                    int r = wm + sm * 16 + q * 4 + reg;
                    cam[base + r * HW] = acc[sm][sn][reg];
                }
            }
        }
    }
}

// ---------------- fused post: stats + inv-norms + pooling (single cam read) -
__global__ __launch_bounds__(256) void post_k(
    float* __restrict__ ws, const float* __restrict__ b0,
    const float* __restrict__ b1, const float* __restrict__ b2,
    float* __restrict__ out) {
    __shared__ float plds[4 * 784];
    int gw = blockIdx.x * 4 + (threadIdx.x >> 6);  // < 24576
    int lane = threadIdx.x & 63;
    float* myl = plds + (threadIdx.x >> 6) * 784;
    int lvl = gw >> 13, row = gw & 8191;           // row = b*128 + r
    const int HW = (lvl == 0) ? 784 : (lvl == 1) ? 196 : 49;
    const float* cam = ws + ((lvl == 0) ? CAM0_OFF : (lvl == 1) ? CAM1_OFF : CAM2_OFF)
                        + (long)row * HW;
    float s = 0.f, ss = 0.f;
    for (int j = lane; j < HW; j += 64) {
        float v = cam[j]; s += v; ss += v * v; myl[j] = v;
    }
#pragma unroll
    for (int o = 32; o; o >>= 1) { s += __shfl_xor(s, o); ss += __shfl_xor(ss, o); }
    if (lane == 0) {
        const float* bias = (lvl == 0) ? b0 : (lvl == 1) ? b1 : b2;
        float mean = s / (float)HW;
        out[lvl * 8192 + row] = mean + bias[row & 127];
        float var = fmaxf(ss - s * mean, 0.f) / (float)(HW - 1);
        out[24576 + lvl * 8192 + row] = sqrtf(var);
        if (lvl >= 1)
            ws[NORM_OFF + (lvl - 1) * 8192 + row] = 1.0f / fmaxf(sqrtf(ss), 1e-12f);
    }
    if (lvl <= 1) {
        const int OP = (lvl == 0) ? 196 : 49;
        const int OW = (lvl == 0) ? 14 : 7;
        const int IW = (lvl == 0) ? 28 : 14;
        float vals[4]; float ssp = 0.f; int cnt = 0;
        for (int p = lane; p < OP; p += 64) {
            int oh = p / OW, ow = p - oh * OW;
            int i0 = oh * 2 * IW + ow * 2;
            float v = (myl[i0] + myl[i0 + 1] + myl[i0 + IW] + myl[i0 + IW + 1]) * 0.25f;
            vals[cnt++] = v; ssp += v * v;
        }
#pragma unroll
        for (int o = 32; o; o >>= 1) ssp += __shfl_xor(ssp, o);
        float inv = 1.0f / fmaxf(sqrtf(ssp), 1e-12f);
        float* dst = ws + ((lvl == 0) ? POOL0_OFF : POOL1_OFF) + (long)row * OP;
        cnt = 0;
        for (int p = lane; p < OP; p += 64) dst[p] = vals[cnt++] * inv;
    }
}

// ---------------- link via MFMA, direct global frags (contraction over i) ---
__device__ inline v8bf load_frag8(const float* __restrict__ row, int k0, int K) {
    v8bf f;
    if (k0 + 8 <= K && (K & 3) == 0) {
        float4 a = *(const float4*)(row + k0);
        float4 c = *(const float4*)(row + k0 + 4);
        f[0] = (bf16)a.x; f[1] = (bf16)a.y; f[2] = (bf16)a.z; f[3] = (bf16)a.w;
        f[4] = (bf16)c.x; f[5] = (bf16)c.y; f[6] = (bf16)c.z; f[7] = (bf16)c.w;
    } else {
#pragma unroll
        for (int j = 0; j < 8; ++j)
            f[j] = (k0 + j < K) ? (bf16)row[k0 + j] : (bf16)0.f;
    }
    return f;
}

// block per (lk, b, m-half): 64m x 128n. Partials stored [b][lk*16384+m*128+n]
// (n fastest within a block -> coalesced 64B-segment writes; reducer reads
// wave-coalesced lines strided over b). hi inv-norm applied here.
__global__ __launch_bounds__(256) void link_mfma_k(const float* __restrict__ ws,
                                                   float* __restrict__ part) {
    int bid = blockIdx.x, tid = threadIdx.x;
    int lk = bid >> 7, rem = bid & 127;
    int b = rem >> 1, mh = rem & 1;
    const int K = lk ? 49 : 196;
    const float* lo = ws + (lk ? POOL1_OFF : POOL0_OFF) + (long)(b * 128 + mh * 64) * K;
    const float* hi = ws + (lk ? CAM2_OFF : CAM1_OFF) + (long)b * 128 * K;
    const float* nrmp = ws + NORM_OFF + lk * 8192 + b * 128;
    int lane = tid & 63, wv = tid >> 6;
    int lm = lane & 15, q = lane >> 4;
    int wm = (wv >> 1) * 32, wn = (wv & 1) * 64;
    f4v acc[2][4] = {};
    for (int kc = 0; kc < K; kc += 32) {
        v8bf af[2], bff[4];
#pragma unroll
        for (int sm = 0; sm < 2; ++sm)
            af[sm] = load_frag8(lo + (long)(wm + sm * 16 + lm) * K, kc + q * 8, K);
#pragma unroll
        for (int sn = 0; sn < 4; ++sn)
            bff[sn] = load_frag8(hi + (long)(wn + sn * 16 + lm) * K, kc + q * 8, K);
#pragma unroll
        for (int sm = 0; sm < 2; ++sm)
#pragma unroll
            for (int sn = 0; sn < 4; ++sn)
                acc[sm][sn] = __builtin_amdgcn_mfma_f32_16x16x32_bf16(
                    af[sm], bff[sn], acc[sm][sn], 0, 0, 0);
    }
    float* pb = part + (long)b * 32768 + lk * 16384;
#pragma unroll
    for (int sn = 0; sn < 4; ++sn) {
        int n = wn + sn * 16 + lm;
        float sh = nrmp[n];
#pragma unroll
        for (int sm = 0; sm < 2; ++sm) {
#pragma unroll
            for (int reg = 0; reg < 4; ++reg) {
                int m = mh * 64 + wm + sm * 16 + q * 4 + reg;
                pb[m * 128 + n] = acc[sm][sn][reg] * sh;
            }
        }
    }
}

// ---------------- reduce partials over b (wave-coalesced lines), /B --------
__global__ void linkred_k(const float* __restrict__ part, float* __restrict__ out) {
    int id = blockIdx.x * 256 + threadIdx.x;  // < 32768 = 2*16384
    float s0 = 0.f, s1 = 0.f, s2 = 0.f, s3 = 0.f;
#pragma unroll
    for (int b = 0; b < 64; b += 4) {
        s0 += part[(long)(b + 0) * 32768 + id];
        s1 += part[(long)(b + 1) * 32768 + id];
        s2 += part[(long)(b + 2) * 32768 + id];
        s3 += part[(long)(b + 3) * 32768 + id];
    }
    out[49152 + id] = (s0 + s1 + s2 + s3) * (1.0f / 64.0f);
}

extern "C" void kernel_launch(void* const* d_in, const int* in_sizes, int n_in,
                              void* d_out, int out_size, void* d_ws, size_t ws_size,
                              hipStream_t stream) {
    const float* f0 = (const float*)d_in[0];
    const float* w0 = (const float*)d_in[1];
    const float* b0 = (const float*)d_in[2];
    const float* f1 = (const float*)d_in[3];
    const float* w1 = (const float*)d_in[4];
    const float* b1 = (const float*)d_in[5];
    const float* f2 = (const float*)d_in[6];
    const float* w2 = (const float*)d_in[7];
    const float* b2 = (const float*)d_in[8];
    float* ws = (float*)d_ws;
    float* out = (float*)d_out;
    bf16* wb = (bf16*)(ws + WB_OFF);

    prep_w<<<1792, 256, 0, stream>>>(w0, w1, w2, wb);
    cam_gemm<<<1152, 512, 0, stream>>>(f0, f1, f2, wb, ws);
    post_k<<<6144, 256, 0, stream>>>(ws, b0, b1, b2, out);
    link_mfma_k<<<256, 256, 0, stream>>>(ws, ws + PART_OFF);
    linkred_k<<<128, 256, 0, stream>>>(ws + PART_OFF, out);
}

// Round 5
// 285.623 us; speedup vs baseline: 1.0519x; 1.0519x over previous
//
#include <hip/hip_runtime.h>
#include <stdint.h>

#define R 128
#define NB 64

// workspace float offsets (total 4,341,760 floats ~= 16.6 MiB)
#define CAM1_OFF  0          // 8192*196 = 1605632
#define CAM2_OFF  1605632    // 8192*49  = 401408
#define POOL0_OFF 2007040    // 8192*196 = 1605632 (pooled cam0, UNnormalized)
#define POOL1_OFF 3612672    // 8192*49  = 401408  (pooled cam1, UNnormalized)
#define WB_OFF    4014080    // 458752 bf16 = 229376 float slots
#define ACCS_OFF  4243456    // 3*8192 row sums      (zeroed by prep_w)
#define ACCQ_OFF  4268032    // 3*8192 row sumsq     (zeroed by prep_w)
#define PSQ_OFF   4292608    // 2*8192 pooled sumsq  (zeroed by prep_w)
#define INVHI_OFF 4308992    // 2*8192 1/||cam row|| (cam1, cam2)
#define INVLO_OFF 4325376    // 2*8192 (1/64)/||pool row|| (pool0, pool1)

typedef __bf16 bf16;
typedef bf16 v2bf __attribute__((ext_vector_type(2)));
typedef bf16 v8bf __attribute__((ext_vector_type(8)));
typedef float f4v __attribute__((ext_vector_type(4)));

// lgkm-only barrier: keeps global loads in flight across the barrier
#define ASM_BARRIER() asm volatile("s_waitcnt lgkmcnt(0)\n\ts_barrier" ::: "memory")

// ---------------- prep: w fp32 -> bf16 + zero accumulators + zero link out --
__global__ void prep_w(const float* __restrict__ w0, const float* __restrict__ w1,
                       const float* __restrict__ w2, bf16* __restrict__ wb,
                       float* __restrict__ ws, float* __restrict__ out) {
    int id = blockIdx.x * 256 + threadIdx.x;   // < 458752 exact
    if (id < 65536) ws[ACCS_OFF + id] = 0.f;   // accS(24576)+accQ(24576)+psq(16384)
    if (id < 32768) out[49152 + id] = 0.f;     // link outputs (atomicAdd targets)
    float v;
    if (id < 65536)       v = w0[id];
    else if (id < 196608) v = w1[id - 65536];
    else                  v = w2[id - 196608];
    wb[id] = (bf16)v;
}

// ---------------- cam GEMM fused: cam[b,r,i] = sum_c w[r,c]*fmap[b,c,i] -----
// 512 threads (8 waves 32m x 32n), BM=128 BN=64 BK=64, double-buffered LDS,
// depth-4 register prefetch, lgkm-only barrier per K-iter (round-1 schedule).
// i-tiles pooling-aligned: lvl0 14x56, lvl1 {56,56,56,28}, lvl2 1x49.
// Fused epilogue (via LDS f32 tile): row sum/sumsq atomics (stats), 2x2
// pooled writes + pooled-sumsq atomics; cam1/cam2 stored, cam0 NEVER stored.
__global__ __launch_bounds__(512) void cam_gemm(
    const float* __restrict__ f0, const float* __restrict__ f1,
    const float* __restrict__ f2, const bf16* __restrict__ wb,
    float* __restrict__ ws) {
    __shared__ __align__(16) char ldsRaw[34816];  // staging 18432 B | f32 tile 128x68
#define LBUF(u) ((bf16*)ldsRaw + (u) * (64 * 72))

    int bid = blockIdx.x, tid = threadIdx.x;
    int lvl, b, i0, VW;
    if (bid < 64)       { lvl = 2; b = bid; i0 = 0; VW = 49; }     // heavy first
    else if (bid < 320) { int t = bid - 64; lvl = 1; b = t >> 2;
                          int ti = t & 3; i0 = ti * 56; VW = ti < 3 ? 56 : 28; }
    else                { int t = bid - 320; lvl = 0; b = t / 14;
                          int ti = t - b * 14; i0 = ti * 56; VW = 56; }
    const int C  = (lvl == 0) ? 512 : (lvl == 1) ? 1024 : 2048;
    const int HW = (lvl == 0) ? 784 : (lvl == 1) ? 196  : 49;
    const float* fmap = (lvl == 0) ? f0 : (lvl == 1) ? f1 : f2;
    const bf16*  wbl  = wb + ((lvl == 0) ? 0 : (lvl == 1) ? 65536 : 196608);

    // staging decode: 1 unit/thread; unit = 2 k-rows x 4 i
    int d = tid >> 4;                 // k-pair id 0..31
    int ku2 = d * 2;
    int i4 = (tid & 15) * 4;
    int i4eff = min(i4, VW - 4);      // clamp keeps float4 loads in-row (56/28 tiles)
    int gbase = b * C * HW + ku2 * HW + i0 + i4eff;
    int ldsd[4];
    int i4c[4];
#pragma unroll
    for (int e = 0; e < 4; ++e) {
        int i = i4 + e;               // LDS row (n-local)
        int grp = (d >> 2) ^ ((i >> 3) & 7);
        ldsd[e] = i * 72 + grp * 8 + (d & 3) * 2;   // bf16 units
        i4c[e] = min(i, 48);          // clamp for HW==49 path
    }
    const int lane = tid & 63, wave = tid >> 6;
    const int lm = lane & 15, q = lane >> 4;
    const int wm = (wave >> 1) * 32, wn = (wave & 1) * 32;
    int irow[2], ixor[2];
#pragma unroll
    for (int sn = 0; sn < 2; ++sn) {
        irow[sn] = wn + sn * 16 + lm;
        ixor[sn] = (irow[sn] >> 3) & 7;
    }
    const bf16* arow[2];
#pragma unroll
    for (int sm = 0; sm < 2; ++sm)
        arow[sm] = wbl + (wm + sm * 16 + lm) * C + q * 8;

    auto loadT = [&](int kc, float4 (&r)[2]) {
        if (lvl != 2) {
            const float* p = fmap + gbase + kc * HW;
            r[0] = *(const float4*)p;
            r[1] = *(const float4*)(p + HW);
        } else {
            const float* p = fmap + b * C * 49 + (kc + ku2) * 49;
            r[0].x = p[i4c[0]]; r[0].y = p[i4c[1]];
            r[0].z = p[i4c[2]]; r[0].w = p[i4c[3]];
            r[1].x = p[49 + i4c[0]]; r[1].y = p[49 + i4c[1]];
            r[1].z = p[49 + i4c[2]]; r[1].w = p[49 + i4c[3]];
        }
    };
    auto stage = [&](float4 (&r)[2], bf16* buf) {
        v2bf t0 = { (bf16)r[0].x, (bf16)r[1].x };
        v2bf t1 = { (bf16)r[0].y, (bf16)r[1].y };
        v2bf t2 = { (bf16)r[0].z, (bf16)r[1].z };
        v2bf t3 = { (bf16)r[0].w, (bf16)r[1].w };
        *(v2bf*)&buf[ldsd[0]] = t0;
        *(v2bf*)&buf[ldsd[1]] = t1;
        *(v2bf*)&buf[ldsd[2]] = t2;
        *(v2bf*)&buf[ldsd[3]] = t3;
    };

    f4v acc[2][2] = {};
    auto comp = [&](int kc, const bf16* buf) {
#pragma unroll
        for (int ks = 0; ks < 64; ks += 32) {
            v8bf af[2];
#pragma unroll
            for (int sm = 0; sm < 2; ++sm)
                af[sm] = *(const v8bf*)(arow[sm] + kc + ks);
            v8bf bfr[2];
#pragma unroll
            for (int sn = 0; sn < 2; ++sn) {
                int grp = (q + ((ks >> 5) << 2)) ^ ixor[sn];
                bfr[sn] = *(const v8bf*)&buf[irow[sn] * 72 + grp * 8];
            }
#pragma unroll
            for (int sm = 0; sm < 2; ++sm)
#pragma unroll
                for (int sn = 0; sn < 2; ++sn)
                    acc[sm][sn] = __builtin_amdgcn_mfma_f32_16x16x32_bf16(
                        af[sm], bfr[sn], acc[sm][sn], 0, 0, 0);
        }
    };

    const int nIter = C >> 6;       // 8 / 16 / 32, divisible by 4
    float4 rT[4][2];
    loadT(0, rT[0]); loadT(64, rT[1]); loadT(128, rT[2]); loadT(192, rT[3]);
    for (int t = 0; t < nIter; t += 4) {
#pragma unroll
        for (int u = 0; u < 4; ++u) {
            stage(rT[u], LBUF(u & 1));
            ASM_BARRIER();
            if (t + u + 4 < nIter) loadT((t + u + 4) << 6, rT[u]);
            comp((t + u) << 6, LBUF(u & 1));
        }
    }

    // ---- fused epilogue: acc -> LDS f32 tile [128][68] ----
    __syncthreads();                          // staging buffers done
    float* tile = (float*)ldsRaw;
#pragma unroll
    for (int sn = 0; sn < 2; ++sn)
#pragma unroll
        for (int sm = 0; sm < 2; ++sm)
#pragma unroll
            for (int reg = 0; reg < 4; ++reg)
                tile[(wm + sm * 16 + q * 4 + reg) * 68 + wn + sn * 16 + lm] =
                    acc[sm][sn][reg];
    __syncthreads();

    int row = tid >> 2, seg = tid & 3;        // 128 rows x 4 col-segments
    long grow = (long)b * 128 + row;
    const float* trow = tile + row * 68;
    float* camrow = (lvl == 1) ? ws + CAM1_OFF + grow * 196 + i0
                  : (lvl == 2) ? ws + CAM2_OFF + grow * 49 : (float*)0;
    float s = 0.f, qq = 0.f;
    const f4v* tr4 = (const f4v*)(trow + seg * 16);
#pragma unroll
    for (int g = 0; g < 4; ++g) {
        f4v v4 = tr4[g];
#pragma unroll
        for (int e = 0; e < 4; ++e) {
            int col = seg * 16 + g * 4 + e;
            if (col < VW) {
                float v = v4[e];
                s += v; qq += v * v;
                if (lvl) camrow[col] = v;
            }
        }
    }
    s += __shfl_xor(s, 1);  s += __shfl_xor(s, 2);
    qq += __shfl_xor(qq, 1); qq += __shfl_xor(qq, 2);
    if (seg == 0) {
        atomicAdd(&ws[ACCS_OFF + lvl * 8192 + grow], s);
        atomicAdd(&ws[ACCQ_OFF + lvl * 8192 + grow], qq);
    }
    // 2x2 pooling (tile widths are pooling-aligned)
    if (lvl == 0) {
        float ps = 0.f;
        float* prow = ws + POOL0_OFF + grow * 196 + (i0 / 56) * 14;
        for (int j = seg; j < 14; j += 4) {
            float v = 0.25f * (trow[2 * j] + trow[2 * j + 1] +
                               trow[28 + 2 * j] + trow[28 + 2 * j + 1]);
            prow[j] = v; ps += v * v;
        }
        ps += __shfl_xor(ps, 1); ps += __shfl_xor(ps, 2);
        if (seg == 0) atomicAdd(&ws[PSQ_OFF + grow], ps);
    } else if (lvl == 1) {
        float ps = 0.f;
        int tt = i0 / 56;                     // 0..3
        int npj = (VW == 56) ? 14 : 7;
        for (int pj = seg; pj < npj; pj += 4) {
            int sub = pj / 7, jj = pj - sub * 7;
            const float* tr2 = trow + sub * 28;
            float v = 0.25f * (tr2[2 * jj] + tr2[2 * jj + 1] +
                               tr2[14 + 2 * jj] + tr2[14 + 2 * jj + 1]);
            ws[POOL1_OFF + grow * 49 + (2 * tt + sub) * 7 + jj] = v;
            ps += v * v;
        }
        ps += __shfl_xor(ps, 1); ps += __shfl_xor(ps, 2);
        if (seg == 0) atomicAdd(&ws[PSQ_OFF + 8192 + grow], ps);
    }
#undef LBUF
}

// ---------------- finalize: embeddings, certainty, inverse norms -----------
__global__ __launch_bounds__(256) void finalize_k(
    float* __restrict__ ws, const float* __restrict__ b0,
    const float* __restrict__ b1, const float* __restrict__ b2,
    float* __restrict__ out) {
    int id = blockIdx.x * 256 + threadIdx.x;   // grid 96 -> 24576 exact
    if (id < 16384) {
        float qn = ws[PSQ_OFF + id];
        ws[INVLO_OFF + id] = (1.0f / 64.0f) / fmaxf(sqrtf(qn), 1e-12f);  // 1/B folded
    }
    int lvl = id >> 13, row = id & 8191;
    float HWf = (lvl == 0) ? 784.f : (lvl == 1) ? 196.f : 49.f;
    float s = ws[ACCS_OFF + id], qq = ws[ACCQ_OFF + id];
    float mean = s / HWf;
    const float* bias = (lvl == 0) ? b0 : (lvl == 1) ? b1 : b2;
    out[id] = mean + bias[row & 127];
    float var = fmaxf(qq - s * mean, 0.f) / (HWf - 1.f);
    out[24576 + id] = sqrtf(var);
    if (lvl >= 1)
        ws[INVHI_OFF + (lvl - 1) * 8192 + row] = 1.0f / fmaxf(sqrtf(qq), 1e-12f);
}

// ---------------- link via MFMA, atomicAdd into out (no part buffer) -------
__device__ inline v8bf load_frag8(const float* __restrict__ row, int k0, int K) {
    v8bf f;
    if (k0 + 8 <= K && (K & 3) == 0) {
        float4 a = *(const float4*)(row + k0);
        float4 c = *(const float4*)(row + k0 + 4);
        f[0] = (bf16)a.x; f[1] = (bf16)a.y; f[2] = (bf16)a.z; f[3] = (bf16)a.w;
        f[4] = (bf16)c.x; f[5] = (bf16)c.y; f[6] = (bf16)c.z; f[7] = (bf16)c.w;
    } else {
#pragma unroll
        for (int j = 0; j < 8; ++j)
            f[j] = (k0 + j < K) ? (bf16)row[k0 + j] : (bf16)0.f;
    }
    return f;
}

// block per (lk, b, m-half): 64m x 128n. Both inv-norms (and 1/B) applied
// here; partials atomicAdd'ed straight into out[49152..].
__global__ __launch_bounds__(256) void link_mfma_k(const float* __restrict__ ws,
                                                   float* __restrict__ out) {
    int bid = blockIdx.x, tid = threadIdx.x;
    int lk = bid >> 7, rem = bid & 127;
    int b = rem >> 1, mh = rem & 1;
    const int K = lk ? 49 : 196;
    const float* lo = ws + (lk ? POOL1_OFF : POOL0_OFF) + (long)(b * 128 + mh * 64) * K;
    const float* hi = ws + (lk ? CAM2_OFF : CAM1_OFF) + (long)b * 128 * K;
    const float* ihi = ws + INVHI_OFF + lk * 8192 + b * 128;
    const float* ilo = ws + INVLO_OFF + lk * 8192 + b * 128 + mh * 64;
    int lane = tid & 63, wv = tid >> 6;
    int lm = lane & 15, q = lane >> 4;
    int wm = (wv >> 1) * 32, wn = (wv & 1) * 64;
    f4v acc[2][4] = {};
    for (int kc = 0; kc < K; kc += 32) {
        v8bf af[2], bff[4];
#pragma unroll
        for (int sm = 0; sm < 2; ++sm)
            af[sm] = load_frag8(lo + (long)(wm + sm * 16 + lm) * K, kc + q * 8, K);
#pragma unroll
        for (int sn = 0; sn < 4; ++sn)
            bff[sn] = load_frag8(hi + (long)(wn + sn * 16 + lm) * K, kc + q * 8, K);
#pragma unroll
        for (int sm = 0; sm < 2; ++sm)
#pragma unroll
            for (int sn = 0; sn < 4; ++sn)
                acc[sm][sn] = __builtin_amdgcn_mfma_f32_16x16x32_bf16(
                    af[sm], bff[sn], acc[sm][sn], 0, 0, 0);
    }
    float fl[2][4];
#pragma unroll
    for (int sm = 0; sm < 2; ++sm)
#pragma unroll
        for (int reg = 0; reg < 4; ++reg)
            fl[sm][reg] = ilo[wm + sm * 16 + q * 4 + reg];
    float* ob = out + 49152 + lk * 16384;
#pragma unroll
    for (int sn = 0; sn < 4; ++sn) {
        int n = wn + sn * 16 + lm;
        float sh = ihi[n];
#pragma unroll
        for (int sm = 0; sm < 2; ++sm) {
#pragma unroll
            for (int reg = 0; reg < 4; ++reg) {
                int m = mh * 64 + wm + sm * 16 + q * 4 + reg;
                atomicAdd(&ob[m * 128 + n], acc[sm][sn][reg] * sh * fl[sm][reg]);
            }
        }
    }
}

extern "C" void kernel_launch(void* const* d_in, const int* in_sizes, int n_in,
                              void* d_out, int out_size, void* d_ws, size_t ws_size,
                              hipStream_t stream) {
    const float* f0 = (const float*)d_in[0];
    const float* w0 = (const float*)d_in[1];
    const float* b0 = (const float*)d_in[2];
    const float* f1 = (const float*)d_in[3];
    const float* w1 = (const float*)d_in[4];
    const float* b1 = (const float*)d_in[5];
    const float* f2 = (const float*)d_in[6];
    const float* w2 = (const float*)d_in[7];
    const float* b2 = (const float*)d_in[8];
    float* ws = (float*)d_ws;
    float* out = (float*)d_out;
    bf16* wb = (bf16*)(ws + WB_OFF);

    prep_w<<<1792, 256, 0, stream>>>(w0, w1, w2, wb, ws, out);
    cam_gemm<<<1216, 512, 0, stream>>>(f0, f1, f2, wb, ws);
    finalize_k<<<96, 256, 0, stream>>>(ws, b0, b1, b2, out);
    link_mfma_k<<<256, 256, 0, stream>>>(ws, out);
}

// Round 6
// 284.525 us; speedup vs baseline: 1.0560x; 1.0039x over previous
//
#include <hip/hip_runtime.h>
#include <stdint.h>

#define R 128
#define NB 64

// workspace float offsets (total 4,341,760 floats ~= 16.6 MiB)
#define CAM1_OFF  0          // 8192*196 = 1605632
#define CAM2_OFF  1605632    // 8192*49  = 401408
#define POOL0_OFF 2007040    // 8192*196 = 1605632 (pooled cam0, UNnormalized)
#define POOL1_OFF 3612672    // 8192*49  = 401408  (pooled cam1, UNnormalized)
#define WB_OFF    4014080    // 458752 bf16 = 229376 float slots
#define ACCS_OFF  4243456    // 3*8192 row sums      (zeroed by prep_w)
#define ACCQ_OFF  4268032    // 3*8192 row sumsq     (zeroed by prep_w)
#define PSQ_OFF   4292608    // 2*8192 pooled sumsq  (zeroed by prep_w)
#define INVHI_OFF 4308992    // 2*8192 1/||cam row|| (cam1, cam2)
#define INVLO_OFF 4325376    // 2*8192 (1/64)/||pool row|| (pool0, pool1)

typedef __bf16 bf16;
typedef bf16 v2bf __attribute__((ext_vector_type(2)));
typedef bf16 v8bf __attribute__((ext_vector_type(8)));
typedef float f4v __attribute__((ext_vector_type(4)));

// lgkm-only barrier: keeps global loads in flight across the barrier
#define ASM_BARRIER() asm volatile("s_waitcnt lgkmcnt(0)\n\ts_barrier" ::: "memory")

// ---------------- prep: w fp32 -> bf16 + zero accumulators + zero link out --
__global__ void prep_w(const float* __restrict__ w0, const float* __restrict__ w1,
                       const float* __restrict__ w2, bf16* __restrict__ wb,
                       float* __restrict__ ws, float* __restrict__ out) {
    int id = blockIdx.x * 256 + threadIdx.x;   // < 458752 exact
    if (id < 65536) ws[ACCS_OFF + id] = 0.f;   // accS(24576)+accQ(24576)+psq(16384)
    if (id < 32768) out[49152 + id] = 0.f;     // link outputs (atomicAdd targets)
    float v;
    if (id < 65536)       v = w0[id];
    else if (id < 196608) v = w1[id - 65536];
    else                  v = w2[id - 196608];
    wb[id] = (bf16)v;
}

// ---------------- cam GEMM fused: cam[b,r,i] = sum_c w[r,c]*fmap[b,c,i] -----
// 512 threads (8 waves 32m x 32n), BM=128 BN=64 BK=64, double-buffered LDS for
// BOTH operands (A=w tile staged to LDS too -> comp() has ZERO global loads,
// so no per-iter vmcnt drain; staging loads stay in flight, counted waits
// only). Depth-4 register prefetch, lgkm-only barrier per K-iter.
// i-tiles pooling-aligned: lvl0 14x56, lvl1 {56,56,56,28}, lvl2 1x49.
// Fused epilogue (via LDS f32 tile): row sum/sumsq atomics (stats), 2x2
// pooled writes + pooled-sumsq atomics; cam1/cam2 stored, cam0 NEVER stored.
__global__ __launch_bounds__(512) void cam_gemm(
    const float* __restrict__ f0, const float* __restrict__ f1,
    const float* __restrict__ f2, const bf16* __restrict__ wb,
    float* __restrict__ ws) {
    // layout: B bufs [0, 18432), A bufs [18432, 55296); epilogue f32 tile
    // (34816 B) reuses [0, 34816) after a __syncthreads.
    __shared__ __align__(16) char ldsRaw[55296];
#define LBUFB(u) ((bf16*)(ldsRaw + (u) * 9216))
#define LBUFA(u) ((bf16*)(ldsRaw + 18432 + (u) * 18432))

    int bid = blockIdx.x, tid = threadIdx.x;
    int lvl, b, i0, VW;
    if (bid < 64)       { lvl = 2; b = bid; i0 = 0; VW = 49; }     // heavy first
    else if (bid < 320) { int t = bid - 64; lvl = 1; b = t >> 2;
                          int ti = t & 3; i0 = ti * 56; VW = ti < 3 ? 56 : 28; }
    else                { int t = bid - 320; lvl = 0; b = t / 14;
                          int ti = t - b * 14; i0 = ti * 56; VW = 56; }
    const int C  = (lvl == 0) ? 512 : (lvl == 1) ? 1024 : 2048;
    const int HW = (lvl == 0) ? 784 : (lvl == 1) ? 196  : 49;
    const float* fmap = (lvl == 0) ? f0 : (lvl == 1) ? f1 : f2;
    const bf16*  wbl  = wb + ((lvl == 0) ? 0 : (lvl == 1) ? 65536 : 196608);

    // ---- B staging decode: 1 unit/thread; unit = 2 k-rows x 4 i ----
    int d = tid >> 4;                 // k-pair id 0..31
    int ku2 = d * 2;
    int i4 = (tid & 15) * 4;
    int i4eff = min(i4, VW - 4);      // clamp keeps float4 loads in-row (56/28 tiles)
    int gbase = b * C * HW + ku2 * HW + i0 + i4eff;
    int ldsd[4];
    int i4c[4];
#pragma unroll
    for (int e = 0; e < 4; ++e) {
        int i = i4 + e;               // LDS row (n-local)
        int grp = (d >> 2) ^ ((i >> 3) & 7);
        ldsd[e] = i * 72 + grp * 8 + (d & 3) * 2;   // bf16 units
        i4c[e] = min(i, 48);          // clamp for HW==49 path
    }
    // ---- A staging decode: 32 B/thread = 2 chunks of one m-row ----
    int am = tid >> 2;                // 0..127 (m row)
    int akb = (tid & 3) * 16;         // bf16 k-offset within BK
    const bf16* awsrc = wbl + am * C + akb;
    int axor = (am >> 3) & 7;
    int ac0 = (tid & 3) * 2;
    int aldsd0 = am * 72 + ((ac0    ) ^ axor) * 8;
    int aldsd1 = am * 72 + ((ac0 + 1) ^ axor) * 8;

    const int lane = tid & 63, wave = tid >> 6;
    const int lm = lane & 15, q = lane >> 4;
    const int wm = (wave >> 1) * 32, wn = (wave & 1) * 32;
    int irow[2], ixor[2];
#pragma unroll
    for (int sn = 0; sn < 2; ++sn) {
        irow[sn] = wn + sn * 16 + lm;
        ixor[sn] = (irow[sn] >> 3) & 7;
    }
    int arowl[2], axorl[2];
#pragma unroll
    for (int sm = 0; sm < 2; ++sm) {
        arowl[sm] = wm + sm * 16 + lm;
        axorl[sm] = (arowl[sm] >> 3) & 7;
    }

    auto loadT = [&](int kc, float4 (&r)[2]) {
        if (lvl != 2) {
            const float* p = fmap + gbase + kc * HW;
            r[0] = *(const float4*)p;
            r[1] = *(const float4*)(p + HW);
        } else {
            const float* p = fmap + b * C * 49 + (kc + ku2) * 49;
            r[0].x = p[i4c[0]]; r[0].y = p[i4c[1]];
            r[0].z = p[i4c[2]]; r[0].w = p[i4c[3]];
            r[1].x = p[49 + i4c[0]]; r[1].y = p[49 + i4c[1]];
            r[1].z = p[49 + i4c[2]]; r[1].w = p[49 + i4c[3]];
        }
    };
    auto loadW = [&](int kc, v8bf (&w)[2]) {
        w[0] = *(const v8bf*)(awsrc + kc);
        w[1] = *(const v8bf*)(awsrc + kc + 8);
    };
    auto stage = [&](float4 (&r)[2], v8bf (&w)[2], bf16* bufB, bf16* bufA) {
        v2bf t0 = { (bf16)r[0].x, (bf16)r[1].x };
        v2bf t1 = { (bf16)r[0].y, (bf16)r[1].y };
        v2bf t2 = { (bf16)r[0].z, (bf16)r[1].z };
        v2bf t3 = { (bf16)r[0].w, (bf16)r[1].w };
        *(v2bf*)&bufB[ldsd[0]] = t0;
        *(v2bf*)&bufB[ldsd[1]] = t1;
        *(v2bf*)&bufB[ldsd[2]] = t2;
        *(v2bf*)&bufB[ldsd[3]] = t3;
        *(v8bf*)&bufA[aldsd0] = w[0];
        *(v8bf*)&bufA[aldsd1] = w[1];
    };

    f4v acc[2][2] = {};
    auto comp = [&](const bf16* bufB, const bf16* bufA) {
#pragma unroll
        for (int ks = 0; ks < 64; ks += 32) {
            int cq = (ks >> 3) + q;
            v8bf af[2];
#pragma unroll
            for (int sm = 0; sm < 2; ++sm)
                af[sm] = *(const v8bf*)&bufA[arowl[sm] * 72 + (cq ^ axorl[sm]) * 8];
            v8bf bfr[2];
#pragma unroll
            for (int sn = 0; sn < 2; ++sn)
                bfr[sn] = *(const v8bf*)&bufB[irow[sn] * 72 + (cq ^ ixor[sn]) * 8];
#pragma unroll
            for (int sm = 0; sm < 2; ++sm)
#pragma unroll
                for (int sn = 0; sn < 2; ++sn)
                    acc[sm][sn] = __builtin_amdgcn_mfma_f32_16x16x32_bf16(
                        af[sm], bfr[sn], acc[sm][sn], 0, 0, 0);
        }
    };

    const int nIter = C >> 6;       // 8 / 16 / 32, divisible by 4
    float4 rT[4][2];
    v8bf   rW[4][2];
    loadT(0, rT[0]);   loadW(0, rW[0]);
    loadT(64, rT[1]);  loadW(64, rW[1]);
    loadT(128, rT[2]); loadW(128, rW[2]);
    loadT(192, rT[3]); loadW(192, rW[3]);
    for (int t = 0; t < nIter; t += 4) {
#pragma unroll
        for (int u = 0; u < 4; ++u) {
            stage(rT[u], rW[u], LBUFB(u & 1), LBUFA(u & 1));
            ASM_BARRIER();
            if (t + u + 4 < nIter) { loadT((t + u + 4) << 6, rT[u]);
                                     loadW((t + u + 4) << 6, rW[u]); }
            comp(LBUFB(u & 1), LBUFA(u & 1));
        }
    }

    // ---- fused epilogue: acc -> LDS f32 tile [128][68] ----
    __syncthreads();                          // staging buffers done
    float* tile = (float*)ldsRaw;
#pragma unroll
    for (int sn = 0; sn < 2; ++sn)
#pragma unroll
        for (int sm = 0; sm < 2; ++sm)
#pragma unroll
            for (int reg = 0; reg < 4; ++reg)
                tile[(wm + sm * 16 + q * 4 + reg) * 68 + wn + sn * 16 + lm] =
                    acc[sm][sn][reg];
    __syncthreads();

    int row = tid >> 2, seg = tid & 3;        // 128 rows x 4 col-segments
    long grow = (long)b * 128 + row;
    const float* trow = tile + row * 68;
    float* camrow = (lvl == 1) ? ws + CAM1_OFF + grow * 196 + i0
                  : (lvl == 2) ? ws + CAM2_OFF + grow * 49 : (float*)0;
    float s = 0.f, qq = 0.f;
    const f4v* tr4 = (const f4v*)(trow + seg * 16);
#pragma unroll
    for (int g = 0; g < 4; ++g) {
        f4v v4 = tr4[g];
#pragma unroll
        for (int e = 0; e < 4; ++e) {
            int col = seg * 16 + g * 4 + e;
            if (col < VW) {
                float v = v4[e];
                s += v; qq += v * v;
                if (lvl) camrow[col] = v;
            }
        }
    }
    s += __shfl_xor(s, 1);  s += __shfl_xor(s, 2);
    qq += __shfl_xor(qq, 1); qq += __shfl_xor(qq, 2);
    if (seg == 0) {
        atomicAdd(&ws[ACCS_OFF + lvl * 8192 + grow], s);
        atomicAdd(&ws[ACCQ_OFF + lvl * 8192 + grow], qq);
    }
    // 2x2 pooling (tile widths are pooling-aligned)
    if (lvl == 0) {
        float ps = 0.f;
        float* prow = ws + POOL0_OFF + grow * 196 + (i0 / 56) * 14;
        for (int j = seg; j < 14; j += 4) {
            float v = 0.25f * (trow[2 * j] + trow[2 * j + 1] +
                               trow[28 + 2 * j] + trow[28 + 2 * j + 1]);
            prow[j] = v; ps += v * v;
        }
        ps += __shfl_xor(ps, 1); ps += __shfl_xor(ps, 2);
        if (seg == 0) atomicAdd(&ws[PSQ_OFF + grow], ps);
    } else if (lvl == 1) {
        float ps = 0.f;
        int tt = i0 / 56;                     // 0..3
        int npj = (VW == 56) ? 14 : 7;
        for (int pj = seg; pj < npj; pj += 4) {
            int sub = pj / 7, jj = pj - sub * 7;
            const float* tr2 = trow + sub * 28;
            float v = 0.25f * (tr2[2 * jj] + tr2[2 * jj + 1] +
                               tr2[14 + 2 * jj] + tr2[14 + 2 * jj + 1]);
            ws[POOL1_OFF + grow * 49 + (2 * tt + sub) * 7 + jj] = v;
            ps += v * v;
        }
        ps += __shfl_xor(ps, 1); ps += __shfl_xor(ps, 2);
        if (seg == 0) atomicAdd(&ws[PSQ_OFF + 8192 + grow], ps);
    }
#undef LBUFB
#undef LBUFA
}

// ---------------- finalize: embeddings, certainty, inverse norms -----------
__global__ __launch_bounds__(256) void finalize_k(
    float* __restrict__ ws, const float* __restrict__ b0,
    const float* __restrict__ b1, const float* __restrict__ b2,
    float* __restrict__ out) {
    int id = blockIdx.x * 256 + threadIdx.x;   // grid 96 -> 24576 exact
    if (id < 16384) {
        float qn = ws[PSQ_OFF + id];
        ws[INVLO_OFF + id] = (1.0f / 64.0f) / fmaxf(sqrtf(qn), 1e-12f);  // 1/B folded
    }
    int lvl = id >> 13, row = id & 8191;
    float HWf = (lvl == 0) ? 784.f : (lvl == 1) ? 196.f : 49.f;
    float s = ws[ACCS_OFF + id], qq = ws[ACCQ_OFF + id];
    float mean = s / HWf;
    const float* bias = (lvl == 0) ? b0 : (lvl == 1) ? b1 : b2;
    out[id] = mean + bias[row & 127];
    float var = fmaxf(qq - s * mean, 0.f) / (HWf - 1.f);
    out[24576 + id] = sqrtf(var);
    if (lvl >= 1)
        ws[INVHI_OFF + (lvl - 1) * 8192 + row] = 1.0f / fmaxf(sqrtf(qq), 1e-12f);
}

// ---------------- link via MFMA, atomicAdd into out (no part buffer) -------
__device__ inline v8bf load_frag8(const float* __restrict__ row, int k0, int K) {
    v8bf f;
    if (k0 + 8 <= K && (K & 3) == 0) {
        float4 a = *(const float4*)(row + k0);
        float4 c = *(const float4*)(row + k0 + 4);
        f[0] = (bf16)a.x; f[1] = (bf16)a.y; f[2] = (bf16)a.z; f[3] = (bf16)a.w;
        f[4] = (bf16)c.x; f[5] = (bf16)c.y; f[6] = (bf16)c.z; f[7] = (bf16)c.w;
    } else {
#pragma unroll
        for (int j = 0; j < 8; ++j)
            f[j] = (k0 + j < K) ? (bf16)row[k0 + j] : (bf16)0.f;
    }
    return f;
}

// block per (lk, b, m-half): 64m x 128n. Both inv-norms (and 1/B) applied
// here; partials atomicAdd'ed straight into out[49152..].
__global__ __launch_bounds__(256) void link_mfma_k(const float* __restrict__ ws,
                                                   float* __restrict__ out) {
    int bid = blockIdx.x, tid = threadIdx.x;
    int lk = bid >> 7, rem = bid & 127;
    int b = rem >> 1, mh = rem & 1;
    const int K = lk ? 49 : 196;
    const float* lo = ws + (lk ? POOL1_OFF : POOL0_OFF) + (long)(b * 128 + mh * 64) * K;
    const float* hi = ws + (lk ? CAM2_OFF : CAM1_OFF) + (long)b * 128 * K;
    const float* ihi = ws + INVHI_OFF + lk * 8192 + b * 128;
    const float* ilo = ws + INVLO_OFF + lk * 8192 + b * 128 + mh * 64;
    int lane = tid & 63, wv = tid >> 6;
    int lm = lane & 15, q = lane >> 4;
    int wm = (wv >> 1) * 32, wn = (wv & 1) * 64;
    f4v acc[2][4] = {};
    for (int kc = 0; kc < K; kc += 32) {
        v8bf af[2], bff[4];
#pragma unroll
        for (int sm = 0; sm < 2; ++sm)
            af[sm] = load_frag8(lo + (long)(wm + sm * 16 + lm) * K, kc + q * 8, K);
#pragma unroll
        for (int sn = 0; sn < 4; ++sn)
            bff[sn] = load_frag8(hi + (long)(wn + sn * 16 + lm) * K, kc + q * 8, K);
#pragma unroll
        for (int sm = 0; sm < 2; ++sm)
#pragma unroll
            for (int sn = 0; sn < 4; ++sn)
                acc[sm][sn] = __builtin_amdgcn_mfma_f32_16x16x32_bf16(
                    af[sm], bff[sn], acc[sm][sn], 0, 0, 0);
    }
    float fl[2][4];
#pragma unroll
    for (int sm = 0; sm < 2; ++sm)
#pragma unroll
        for (int reg = 0; reg < 4; ++reg)
            fl[sm][reg] = ilo[wm + sm * 16 + q * 4 + reg];
    float* ob = out + 49152 + lk * 16384;
#pragma unroll
    for (int sn = 0; sn < 4; ++sn) {
        int n = wn + sn * 16 + lm;
        float sh = ihi[n];
#pragma unroll
        for (int sm = 0; sm < 2; ++sm) {
#pragma unroll
            for (int reg = 0; reg < 4; ++reg) {
                int m = mh * 64 + wm + sm * 16 + q * 4 + reg;
                atomicAdd(&ob[m * 128 + n], acc[sm][sn][reg] * sh * fl[sm][reg]);
            }
        }
    }
}

extern "C" void kernel_launch(void* const* d_in, const int* in_sizes, int n_in,
                              void* d_out, int out_size, void* d_ws, size_t ws_size,
                              hipStream_t stream) {
    const float* f0 = (const float*)d_in[0];
    const float* w0 = (const float*)d_in[1];
    const float* b0 = (const float*)d_in[2];
    const float* f1 = (const float*)d_in[3];
    const float* w1 = (const float*)d_in[4];
    const float* b1 = (const float*)d_in[5];
    const float* f2 = (const float*)d_in[6];
    const float* w2 = (const float*)d_in[7];
    const float* b2 = (const float*)d_in[8];
    float* ws = (float*)d_ws;
    float* out = (float*)d_out;
    bf16* wb = (bf16*)(ws + WB_OFF);

    prep_w<<<1792, 256, 0, stream>>>(w0, w1, w2, wb, ws, out);
    cam_gemm<<<1216, 512, 0, stream>>>(f0, f1, f2, wb, ws);
    finalize_k<<<96, 256, 0, stream>>>(ws, b0, b1, b2, out);
    link_mfma_k<<<256, 256, 0, stream>>>(ws, out);
}